// Round 8
// baseline (353.875 us; speedup 1.0000x reference)
//
#include <hip/hip_runtime.h>
#include <stdint.h>

#define HW    4096      // 64*64
#define CIN   256
#define COUT  512
#define NSPE  64500
#define NFAM  510
#define NORD  100
#define NOUT  65110     // 64500+510+100
#define NB    512       // megakernel grid: 2 blocks/CU x 256 CU, all resident

typedef __attribute__((ext_vector_type(8))) short bf16x8;
typedef __attribute__((ext_vector_type(4))) float f32x4;
typedef __attribute__((address_space(3))) uint32_t lds_u32;
typedef __attribute__((address_space(1))) const uint32_t glob_u32;

__device__ __forceinline__ short f32_to_bf16(float f) {
    uint32_t u = __float_as_uint(f);
    u += 0x7fffu + ((u >> 16) & 1u);   // RNE
    return (short)(u >> 16);
}
__device__ __forceinline__ float bf16_to_f32(unsigned short s) {
    return __uint_as_float(((uint32_t)s) << 16);
}

// device-scope grid barrier; requires all NB blocks resident (512 = 2/CU).
// bounded spin: on residency failure produces wrong output (diagnostic), not a hang.
__device__ __forceinline__ void grid_barrier(int* bar, int idx) {
    __syncthreads();
    if (threadIdx.x == 0) {
        __threadfence();
        int* cnt  = bar + idx * 2;
        int* flag = bar + idx * 2 + 1;
        int a = __hip_atomic_fetch_add(cnt, 1, __ATOMIC_ACQ_REL,
                                       __HIP_MEMORY_SCOPE_AGENT);
        if (a == NB - 1) {
            __hip_atomic_store(flag, 1, __ATOMIC_RELEASE,
                               __HIP_MEMORY_SCOPE_AGENT);
        } else {
            int it = 0;
            while (!__hip_atomic_load(flag, __ATOMIC_ACQUIRE,
                                      __HIP_MEMORY_SCOPE_AGENT)) {
                __builtin_amdgcn_s_sleep(8);
                if (++it > (1 << 19)) break;   // ~0.1s valve
            }
        }
        __threadfence();
    }
    __syncthreads();
}

union SharedU {
    float conv_lds[32][128];                               // 16 KB
    struct { short As[2][4096]; short Bs[2][4096]; } g;    // 32 KB
    struct { float kS[2][4422]; float vS[2][4422]; float red[4][4]; } a; // 70.8 KB
};

// Tile layout: [128 rows][32 k] bf16, elem (row,k) at
//   row*32 + ((k>>3 ^ ((row>>1)&3))<<3) + (k&7)   (slot-XOR swizzle)

__global__ __launch_bounds__(256, 2) void mega_kernel(
    const float* __restrict__ x,
    const float* __restrict__ wq, const float* __restrict__ bq,
    const float* __restrict__ wk, const float* __restrict__ bk,
    const float* __restrict__ wv, const float* __restrict__ bv,
    const float* __restrict__ rel_h, const float* __restrict__ rel_w,
    const float* __restrict__ w_sp, const float* __restrict__ b_sp,
    const float* __restrict__ w_fa, const float* __restrict__ b_fa,
    const float* __restrict__ w_or, const float* __restrict__ b_or,
    short* __restrict__ Wt, short* __restrict__ Xt,
    short* __restrict__ qkv, float* __restrict__ pooled,
    int* __restrict__ bar, float* __restrict__ out)
{
    __shared__ SharedU sh;
    const int bid = blockIdx.x, tid = threadIdx.x;

    // ================= phase 0: convert (1024 x-tiles + 96 W-tiles) =========
    for (int j = bid; j < 1120; j += NB) {
        __syncthreads();   // protect conv_lds reuse across iterations
        if (j < 1024) {
            const int kt = j & 7, nt = (j >> 3) & 31, b = j >> 8;
            #pragma unroll
            for (int jj = 0; jj < 16; ++jj) {
                int idx = jj * 256 + tid;
                int c = idx >> 7, p = idx & 127;
                sh.conv_lds[c][p] =
                    x[((size_t)b * CIN + kt * 32 + c) * HW + nt * 128 + p];
            }
            __syncthreads();
            const int n = tid >> 1;
            short* o = Xt + (((size_t)(b * 32 + nt) * 8 + kt) << 12);
            union { short s[16]; int4 v[2]; } pk;
            #pragma unroll
            for (int jj = 0; jj < 16; ++jj) {
                int e  = tid * 16 + jj;
                int sp = (e >> 3) & 3;
                int i  = e & 7;
                int k  = ((sp ^ ((n >> 1) & 3)) << 3) + i;
                pk.s[jj] = f32_to_bf16(sh.conv_lds[k][n]);
            }
            int4* dst = (int4*)(o + tid * 16);
            dst[0] = pk.v[0];
            dst[1] = pk.v[1];
        } else {
            const int e9 = j - 1024;              // 0..95
            const int kt = e9 & 7, y = e9 >> 3;   // y = mat*4+mt
            const int mt = y & 3, mat = y >> 2;
            const float* __restrict__ W = (mat == 0) ? wq : (mat == 1) ? wk : wv;
            const int m = tid >> 1;
            short* o = Wt + (((size_t)y * 8 + kt) << 12);
            union { short s[16]; int4 v[2]; } pk;
            #pragma unroll
            for (int jj = 0; jj < 16; ++jj) {
                int e  = tid * 16 + jj;
                int sp = (e >> 3) & 3;
                int i  = e & 7;
                int k  = ((sp ^ ((m >> 1) & 3)) << 3) + i;
                pk.s[jj] = f32_to_bf16(W[(size_t)(mt * 128 + m) * CIN + kt * 32 + k]);
            }
            int4* dst = (int4*)(o + tid * 16);
            dst[0] = pk.v[0];
            dst[1] = pk.v[1];
        }
    }
    grid_barrier(bar, 0);

    // ================= phase 1: GEMM (1536 tile-jobs, 3 per block) ==========
    {
        const int lane = tid & 63, wid = tid >> 6;
        const int wm = wid >> 1, wn = wid & 1;
        const int l15 = lane & 15, sl = lane >> 4;
        const int sw = ((sl ^ ((l15 >> 1) & 3)) << 3);

        for (int j = bid; j < 1536; j += NB) {
            const int nt = j & 31, mt = (j >> 5) & 3, z = j >> 7;
            const int mat = z >> 2, b = z & 3;
            const short* At = Wt + (((size_t)(mat * 4 + mt) * 8) << 12);
            const short* Bt = Xt + (((size_t)(b * 32 + nt) * 8) << 12);

            f32x4 acc[4][4] = {};

#define STAGE(KT, BUF) do {                                                   \
    _Pragma("unroll")                                                         \
    for (int jj = 0; jj < 4; ++jj) {                                          \
        int li = wid * 4 + jj;                                                \
        if (li < 8)                                                           \
            __builtin_amdgcn_global_load_lds(                                 \
                (glob_u32*)(At + (KT) * 4096 + li * 512 + lane * 8),          \
                (lds_u32*)(&sh.g.As[BUF][li * 512]), 16, 0, 0);               \
        else                                                                  \
            __builtin_amdgcn_global_load_lds(                                 \
                (glob_u32*)(Bt + (KT) * 4096 + (li - 8) * 512 + lane * 8),    \
                (lds_u32*)(&sh.g.Bs[BUF][(li - 8) * 512]), 16, 0, 0);         \
    }                                                                         \
} while (0)

            __syncthreads();   // protect LDS reuse from previous job/phase
            STAGE(0, 0);
            __syncthreads();

            int buf = 0;
            #pragma unroll 2
            for (int kt = 0; kt < 8; ++kt) {
                if (kt < 7) STAGE(kt + 1, buf ^ 1);

                bf16x8 a[4], bb[4];
                #pragma unroll
                for (int f = 0; f < 4; ++f) {
                    int ra = wm * 64 + f * 16 + l15;
                    a[f]  = *(const bf16x8*)(&sh.g.As[buf][ra * 32 + sw]);
                    int rb = wn * 64 + f * 16 + l15;
                    bb[f] = *(const bf16x8*)(&sh.g.Bs[buf][rb * 32 + sw]);
                }
                #pragma unroll
                for (int mf = 0; mf < 4; ++mf)
                    #pragma unroll
                    for (int nf = 0; nf < 4; ++nf)
                        acc[mf][nf] = __builtin_amdgcn_mfma_f32_16x16x32_bf16(
                            a[mf], bb[nf], acc[mf][nf], 0, 0, 0);
                __syncthreads();
                buf ^= 1;
            }
#undef STAGE

            const float* bias = (mat == 0) ? bq : (mat == 1) ? bk : bv;
            short* o = qkv + (((size_t)(b * 3 + mat) * COUT + mt * 128) * HW) + nt * 128;
            const int col = lane & 15, g = lane >> 4;
            #pragma unroll
            for (int mf = 0; mf < 4; ++mf) {
                #pragma unroll
                for (int nf = 0; nf < 4; ++nf) {
                    #pragma unroll
                    for (int r = 0; r < 4; ++r) {
                        int m = wm * 64 + mf * 16 + g * 4 + r;
                        int n = wn * 64 + nf * 16 + col;
                        float val = acc[mf][nf][r] + bias[mt * 128 + m];
                        o[(size_t)m * HW + n] = f32_to_bf16(val);
                    }
                }
            }
        }
    }
    grid_barrier(bar, 1);

    // ================= phase 2: attention + relu + pool (c = bid) ===========
    {
        const int c = bid;
        const int h  = tid >> 2;
        const int w0 = (tid & 3) * 16;

        // zero pad borders of both buffers
        #pragma unroll
        for (int bu = 0; bu < 2; ++bu) {
            if (tid < 67) {
                sh.a.kS[bu][tid] = 0.f;            sh.a.vS[bu][tid] = 0.f;
                sh.a.kS[bu][65 * 67 + tid] = 0.f;  sh.a.vS[bu][65 * 67 + tid] = 0.f;
            }
            if (tid < 64) {
                int r0 = (tid + 1) * 67;
                sh.a.kS[bu][r0] = 0.f;       sh.a.vS[bu][r0] = 0.f;
                sh.a.kS[bu][r0 + 65] = 0.f;  sh.a.vS[bu][r0 + 65] = 0.f;
            }
        }

        const bool isH = (c < 256);
        float r3[3];
        #pragma unroll
        for (int i = 0; i < 3; ++i)
            r3[i] = isH ? rel_h[c * 3 + i] : rel_w[(c - 256) * 3 + i];
        float relv[9];
        #pragma unroll
        for (int kh = 0; kh < 3; ++kh)
            #pragma unroll
            for (int kw = 0; kw < 3; ++kw)
                relv[kh * 3 + kw] = isH ? r3[kh] : r3[kw];

        const int y0 = tid >> 3,         xs0 = (tid & 7) * 8;
        const int y1 = (tid + 256) >> 3, xs1 = ((tid + 256) & 7) * 8;

        int4 krg0, krg1, vrg0, vrg1, qn0, qn1;
#define LOADB(B) do {                                                         \
    const unsigned short* kg_ = (const unsigned short*)qkv +                  \
        ((size_t)((B) * 3 + 1) * COUT + c) * HW;                              \
    const unsigned short* vg_ = (const unsigned short*)qkv +                  \
        ((size_t)((B) * 3 + 2) * COUT + c) * HW;                              \
    const unsigned short* qc_ = (const unsigned short*)qkv +                  \
        ((size_t)((B) * 3 + 0) * COUT + c) * HW;                              \
    krg0 = reinterpret_cast<const int4*>(kg_)[tid];                           \
    krg1 = reinterpret_cast<const int4*>(kg_)[tid + 256];                     \
    vrg0 = reinterpret_cast<const int4*>(vg_)[tid];                           \
    vrg1 = reinterpret_cast<const int4*>(vg_)[tid + 256];                     \
    qn0  = reinterpret_cast<const int4*>(qc_ + h * 64 + w0)[0];               \
    qn1  = reinterpret_cast<const int4*>(qc_ + h * 64 + w0)[1];               \
} while (0)

#define WRITEB(BUF) do {                                                      \
    union { int4 v; unsigned short s[8]; } ak_, av_;                          \
    ak_.v = krg0; av_.v = vrg0;                                               \
    _Pragma("unroll")                                                         \
    for (int e = 0; e < 8; ++e) {                                             \
        sh.a.kS[BUF][(y0 + 1) * 67 + xs0 + 1 + e] = bf16_to_f32(ak_.s[e]);    \
        sh.a.vS[BUF][(y0 + 1) * 67 + xs0 + 1 + e] = bf16_to_f32(av_.s[e]);    \
    }                                                                         \
    ak_.v = krg1; av_.v = vrg1;                                               \
    _Pragma("unroll")                                                         \
    for (int e = 0; e < 8; ++e) {                                             \
        sh.a.kS[BUF][(y1 + 1) * 67 + xs1 + 1 + e] = bf16_to_f32(ak_.s[e]);    \
        sh.a.vS[BUF][(y1 + 1) * 67 + xs1 + 1 + e] = bf16_to_f32(av_.s[e]);    \
    }                                                                         \
} while (0)

        LOADB(0);
        WRITEB(0);

        #pragma unroll
        for (int b = 0; b < 4; ++b) {
            const int buf = b & 1;

            float qf[16];
            {
                union { int4 v[2]; unsigned short s[16]; } qu;
                qu.v[0] = qn0; qu.v[1] = qn1;
                #pragma unroll
                for (int i = 0; i < 16; ++i)
                    qf[i] = bf16_to_f32(qu.s[i]) * 1.4426950408889634f;
            }

            if (b < 3) LOADB(b + 1);

            __syncthreads();

            const float* krow = &sh.a.kS[buf][h * 67 + w0];
            const float* vrow = &sh.a.vS[buf][h * 67 + w0];

            float kcw[3][3], vcw[3][3];
            #pragma unroll
            for (int s = 0; s < 2; ++s)
                #pragma unroll
                for (int r = 0; r < 3; ++r) {
                    kcw[s][r] = krow[r * 67 + s];
                    vcw[s][r] = vrow[r * 67 + s];
                }

            float total = 0.f;
            #pragma unroll
            for (int i = 0; i < 16; ++i) {
                const int s2 = (i + 2) % 3;
                #pragma unroll
                for (int r = 0; r < 3; ++r) {
                    kcw[s2][r] = krow[r * 67 + i + 2];
                    vcw[s2][r] = vrow[r * 67 + i + 2];
                }
                const float q2 = qf[i];
                float num = 0.f, den = 0.f;
                #pragma unroll
                for (int r = 0; r < 3; ++r)
                    #pragma unroll
                    for (int dx = 0; dx < 3; ++dx) {
                        const int sl = (i + dx) % 3;
                        float e = __builtin_exp2f(q2 * (kcw[sl][r] + relv[r * 3 + dx]));
                        den += e;
                        num = fmaf(e, vcw[sl][r], num);
                    }
                total += fmaxf(num * __builtin_amdgcn_rcpf(den), 0.f);
            }

            if (b < 3) WRITEB(buf ^ 1);

            #pragma unroll
            for (int off = 32; off; off >>= 1) total += __shfl_down(total, off);
            if ((tid & 63) == 0) sh.a.red[b][tid >> 6] = total;
        }
#undef LOADB
#undef WRITEB

        __syncthreads();
        if (tid < 4)
            pooled[tid * COUT + c] =
                (sh.a.red[tid][0] + sh.a.red[tid][1] +
                 sh.a.red[tid][2] + sh.a.red[tid][3]) * (1.f / 4096.f);
    }
    grid_barrier(bar, 2);

    // ================= phase 3: classifier heads ============================
    {
        const int lane   = tid & 63;
        const int wave   = bid * 4 + (tid >> 6);
        const int nwaves = NB * 4;

        float pr[4][8];
        #pragma unroll
        for (int b = 0; b < 4; ++b)
            #pragma unroll
            for (int e = 0; e < 8; ++e)
                pr[b][e] = pooled[b * COUT + lane * 8 + e];

        for (int j = wave; j < NOUT; j += nwaves) {
            const float* __restrict__ wrow;
            float bias;
            if (j < NSPE)            { wrow = w_sp + (size_t)j * COUT;          bias = b_sp[j]; }
            else if (j < NSPE + NFAM){ wrow = w_fa + (size_t)(j - NSPE) * COUT; bias = b_fa[j - NSPE]; }
            else                     { wrow = w_or + (size_t)(j - NSPE - NFAM) * COUT; bias = b_or[j - NSPE - NFAM]; }

            const float4 w0 = reinterpret_cast<const float4*>(wrow)[lane * 2 + 0];
            const float4 w1 = reinterpret_cast<const float4*>(wrow)[lane * 2 + 1];
            const float we[8] = {w0.x, w0.y, w0.z, w0.w, w1.x, w1.y, w1.z, w1.w};

            float a0 = 0.f, a1 = 0.f, a2 = 0.f, a3 = 0.f;
            #pragma unroll
            for (int e = 0; e < 8; ++e) {
                a0 += we[e] * pr[0][e];
                a1 += we[e] * pr[1][e];
                a2 += we[e] * pr[2][e];
                a3 += we[e] * pr[3][e];
            }
            #pragma unroll
            for (int off = 32; off; off >>= 1) {
                a0 += __shfl_down(a0, off);
                a1 += __shfl_down(a1, off);
                a2 += __shfl_down(a2, off);
                a3 += __shfl_down(a3, off);
            }
            if (lane == 0) {
                out[0 * NOUT + j] = a0 + bias;
                out[1 * NOUT + j] = a1 + bias;
                out[2 * NOUT + j] = a2 + bias;
                out[3 * NOUT + j] = a3 + bias;
            }
        }
    }
}

extern "C" void kernel_launch(void* const* d_in, const int* in_sizes, int n_in,
                              void* d_out, int out_size, void* d_ws, size_t ws_size,
                              hipStream_t stream) {
    const float* x     = (const float*)d_in[0];
    const float* wq    = (const float*)d_in[1];
    const float* bq    = (const float*)d_in[2];
    const float* wk    = (const float*)d_in[3];
    const float* bk    = (const float*)d_in[4];
    const float* wv    = (const float*)d_in[5];
    const float* bv    = (const float*)d_in[6];
    const float* rel_h = (const float*)d_in[7];
    const float* rel_w = (const float*)d_in[8];
    const float* w_sp  = (const float*)d_in[9];
    const float* b_sp  = (const float*)d_in[10];
    const float* w_fa  = (const float*)d_in[11];
    const float* b_fa  = (const float*)d_in[12];
    const float* w_or  = (const float*)d_in[13];
    const float* b_or  = (const float*)d_in[14];
    float* out = (float*)d_out;

    // ws: Wt bf16 | Xt bf16 | qkv bf16 | pooled f32 | barrier ints
    short* Wt  = (short*)d_ws;                       // 3*512*256   = 393216
    short* Xt  = Wt + 393216;                        // 4*256*4096  = 4194304
    short* qkv = Xt + 4194304;                       // 4*3*512*4096= 25165824
    float* pooled = (float*)(qkv + 25165824);        // 4*512
    int*   bar    = (int*)(pooled + 2048);           // 3 x {cnt,flag}

    hipMemsetAsync(bar, 0, 6 * sizeof(int), stream);
    mega_kernel<<<dim3(NB), 256, 0, stream>>>(
        x, wq, bq, wk, bk, wv, bv, rel_h, rel_w,
        w_sp, b_sp, w_fa, b_fa, w_or, b_or,
        Wt, Xt, qkv, pooled, bar, out);
}

// Round 9
// 88.409 us; speedup vs baseline: 4.0027x; 4.0027x over previous
//
#include <hip/hip_runtime.h>
#include <stdint.h>

#define HW    4096      // 64*64
#define CIN   256
#define COUT  512
#define NSPE  64500
#define NFAM  510
#define NORD  100
#define NOUT  65110     // 64500+510+100

typedef __attribute__((ext_vector_type(8))) short bf16x8;
typedef __attribute__((ext_vector_type(4))) float f32x4;
typedef __attribute__((address_space(3))) uint32_t lds_u32;
typedef __attribute__((address_space(1))) const uint32_t glob_u32;

__device__ __forceinline__ short f32_to_bf16(float f) {
    uint32_t u = __float_as_uint(f);
    u += 0x7fffu + ((u >> 16) & 1u);   // RNE
    return (short)(u >> 16);
}
__device__ __forceinline__ float bf16_to_f32(unsigned short s) {
    return __uint_as_float(((uint32_t)s) << 16);
}

// Tile layout: [128 rows][32 k] bf16, element (row,k) stored at
//   row*32 + ((k>>3 ^ ((row>>1)&3))<<3) + (k&7)     (slot-XOR swizzle)

// ---- unified convert: z<4 -> x slices (batch z), z==4 -> weights ----
__global__ __launch_bounds__(256) void convert_kernel(
    const float* __restrict__ x,
    const float* __restrict__ wq, const float* __restrict__ wk,
    const float* __restrict__ wv,
    short* __restrict__ Xt, short* __restrict__ Wt)
{
    const int t = threadIdx.x;
    __shared__ float lds[32][128];

    if (blockIdx.z < 4) {
        const int kt = blockIdx.x, nt = blockIdx.y, b = blockIdx.z;
        #pragma unroll
        for (int j = 0; j < 16; ++j) {
            int idx = j * 256 + t;
            int c = idx >> 7, p = idx & 127;
            lds[c][p] = x[((size_t)b * CIN + kt * 32 + c) * HW + nt * 128 + p];
        }
        __syncthreads();

        const int n = t >> 1;
        short* out = Xt + (((size_t)(b * 32 + nt) * 8 + kt) << 12);
        union { short s[16]; int4 v[2]; } pk;
        #pragma unroll
        for (int j = 0; j < 16; ++j) {
            int e  = t * 16 + j;
            int sp = (e >> 3) & 3;
            int i  = e & 7;
            int k  = ((sp ^ ((n >> 1) & 3)) << 3) + i;
            pk.s[j] = f32_to_bf16(lds[k][n]);
        }
        int4* dst = (int4*)(out + t * 16);
        dst[0] = pk.v[0];
        dst[1] = pk.v[1];
    } else {
        if (blockIdx.y >= 12) return;
        const int kt = blockIdx.x, mt = blockIdx.y & 3, mat = blockIdx.y >> 2;
        const float* __restrict__ W = (mat == 0) ? wq : (mat == 1) ? wk : wv;
        const int m = t >> 1;
        short* out = Wt + (((size_t)(mat * 4 + mt) * 8 + kt) << 12);

        union { short s[16]; int4 v[2]; } pk;
        #pragma unroll
        for (int j = 0; j < 16; ++j) {
            int e  = t * 16 + j;
            int sp = (e >> 3) & 3;
            int i  = e & 7;
            int k  = ((sp ^ ((m >> 1) & 3)) << 3) + i;
            pk.s[j] = f32_to_bf16(W[(size_t)(mt * 128 + m) * CIN + kt * 32 + k]);
        }
        int4* dst = (int4*)(out + t * 16);
        dst[0] = pk.v[0];
        dst[1] = pk.v[1];
    }
}

// ---- QKV GEMM (R4 config: BM=BN=128, BK=32, 4 waves 2x2, dbuf) ----
__global__ __launch_bounds__(256) void qkv_mfma_kernel(
    const short* __restrict__ Wt, const short* __restrict__ Xt,
    const float* __restrict__ bq, const float* __restrict__ bk,
    const float* __restrict__ bv, short* __restrict__ qkv)
{
    const int nt = blockIdx.x, mt = blockIdx.y, z = blockIdx.z;
    const int mat = z >> 2, b = z & 3;
    const short* At = Wt + (((size_t)(mat * 4 + mt) * 8) << 12);
    const short* Bt = Xt + (((size_t)(b * 32 + nt) * 8) << 12);

    __shared__ __align__(16) short As[2][4096];
    __shared__ __align__(16) short Bs[2][4096];

    const int tid = threadIdx.x, lane = tid & 63, wid = tid >> 6;
    const int wm = wid >> 1, wn = wid & 1;
    const int l15 = lane & 15, sl = lane >> 4;
    const int sw = ((sl ^ ((l15 >> 1) & 3)) << 3);

    f32x4 acc[4][4] = {};

#define STAGE(KT, BUF) do {                                                   \
    _Pragma("unroll")                                                         \
    for (int j = 0; j < 4; ++j) {                                             \
        int li = wid * 4 + j;                                                 \
        if (li < 8)                                                           \
            __builtin_amdgcn_global_load_lds(                                 \
                (glob_u32*)(At + (KT) * 4096 + li * 512 + lane * 8),          \
                (lds_u32*)(&As[BUF][li * 512]), 16, 0, 0);                    \
        else                                                                  \
            __builtin_amdgcn_global_load_lds(                                 \
                (glob_u32*)(Bt + (KT) * 4096 + (li - 8) * 512 + lane * 8),    \
                (lds_u32*)(&Bs[BUF][(li - 8) * 512]), 16, 0, 0);              \
    }                                                                         \
} while (0)

    STAGE(0, 0);
    __syncthreads();

    int buf = 0;
    #pragma unroll 2
    for (int kt = 0; kt < 8; ++kt) {
        if (kt < 7) STAGE(kt + 1, buf ^ 1);

        bf16x8 a[4], bb[4];
        #pragma unroll
        for (int f = 0; f < 4; ++f) {
            int ra = wm * 64 + f * 16 + l15;
            a[f]  = *(const bf16x8*)(&As[buf][ra * 32 + sw]);
            int rb = wn * 64 + f * 16 + l15;
            bb[f] = *(const bf16x8*)(&Bs[buf][rb * 32 + sw]);
        }
        #pragma unroll
        for (int mf = 0; mf < 4; ++mf)
            #pragma unroll
            for (int nf = 0; nf < 4; ++nf)
                acc[mf][nf] = __builtin_amdgcn_mfma_f32_16x16x32_bf16(
                    a[mf], bb[nf], acc[mf][nf], 0, 0, 0);
        __syncthreads();
        buf ^= 1;
    }
#undef STAGE

    const float* bias = (mat == 0) ? bq : (mat == 1) ? bk : bv;
    short* out = qkv + (((size_t)(b * 3 + mat) * COUT + mt * 128) * HW) + nt * 128;
    const int col = lane & 15, g = lane >> 4;
    #pragma unroll
    for (int mf = 0; mf < 4; ++mf) {
        #pragma unroll
        for (int nf = 0; nf < 4; ++nf) {
            #pragma unroll
            for (int r = 0; r < 4; ++r) {
                int m = wm * 64 + mf * 16 + g * 4 + r;
                int n = wn * 64 + nf * 16 + col;
                float val = acc[mf][nf][r] + bias[mt * 128 + m];
                out[(size_t)m * HW + n] = f32_to_bf16(val);
            }
        }
    }
}

// ---- attention + relu + pool: one block per CHANNEL, pipelined b-loop ----
// k,v kept as bf16 in LDS (stride 70: reads ~conflict-free, writes b32-packed),
// zero halo at rows 0/65 and cols 3/68; data cols 4..67. LDS 37 KB -> 4 blocks/CU.
__global__ __launch_bounds__(256, 4) void attn_pool_kernel(
    const unsigned short* __restrict__ qkv,
    const float* __restrict__ rel_h, const float* __restrict__ rel_w,
    float* __restrict__ pooled)   // [4][COUT]
{
    const int c = blockIdx.x;
    const int tid = threadIdx.x;
    const int h  = tid >> 2;            // 0..63
    const int w0 = (tid & 3) * 16;      // 0,16,32,48

    __shared__ unsigned short kS[2][66 * 70];
    __shared__ unsigned short vS[2][66 * 70];
    __shared__ float red[4][4];

    // zero halo of BOTH buffers (written once, never overwritten)
    #pragma unroll
    for (int bu = 0; bu < 2; ++bu) {
        if (tid < 70) {
            kS[bu][tid] = 0;            vS[bu][tid] = 0;             // row -1
            kS[bu][65 * 70 + tid] = 0;  vS[bu][65 * 70 + tid] = 0;   // row 64
        }
        if (tid < 64) {
            int r0 = (tid + 1) * 70;
            kS[bu][r0 + 3] = 0;   vS[bu][r0 + 3] = 0;                // col -1
            kS[bu][r0 + 68] = 0;  vS[bu][r0 + 68] = 0;               // col 64
        }
    }

    const bool isH = (c < 256);
    float r3[3];
    #pragma unroll
    for (int i = 0; i < 3; ++i)
        r3[i] = isH ? rel_h[c * 3 + i] : rel_w[(c - 256) * 3 + i];
    float relv[9];
    #pragma unroll
    for (int kh = 0; kh < 3; ++kh)
        #pragma unroll
        for (int kw = 0; kw < 3; ++kw)
            relv[kh * 3 + kw] = isH ? r3[kh] : r3[kw];

    const int y0 = tid >> 3,         xs0 = (tid & 7) * 8;
    const int y1 = (tid + 256) >> 3, xs1 = ((tid + 256) & 7) * 8;

    int4 krg0, krg1, vrg0, vrg1, qn0, qn1;
#define LOADB(B) do {                                                         \
    const unsigned short* kg_ = qkv + ((size_t)((B) * 3 + 1) * COUT + c) * HW;\
    const unsigned short* vg_ = qkv + ((size_t)((B) * 3 + 2) * COUT + c) * HW;\
    const unsigned short* qc_ = qkv + ((size_t)((B) * 3 + 0) * COUT + c) * HW;\
    krg0 = reinterpret_cast<const int4*>(kg_)[tid];                           \
    krg1 = reinterpret_cast<const int4*>(kg_)[tid + 256];                     \
    vrg0 = reinterpret_cast<const int4*>(vg_)[tid];                           \
    vrg1 = reinterpret_cast<const int4*>(vg_)[tid + 256];                     \
    qn0  = reinterpret_cast<const int4*>(qc_ + h * 64 + w0)[0];               \
    qn1  = reinterpret_cast<const int4*>(qc_ + h * 64 + w0)[1];               \
} while (0)

// store 8 bf16 (one int4) as 4 packed b32 writes; u16 index (row*70+4+xs+2e) is even
#define WRITEB(BUF) do {                                                      \
    union { int4 v; uint32_t u[4]; } ak_, av_;                                \
    ak_.v = krg0; av_.v = vrg0;                                               \
    _Pragma("unroll")                                                         \
    for (int e = 0; e < 4; ++e) {                                             \
        *(uint32_t*)&kS[BUF][(y0 + 1) * 70 + 4 + xs0 + 2 * e] = ak_.u[e];     \
        *(uint32_t*)&vS[BUF][(y0 + 1) * 70 + 4 + xs0 + 2 * e] = av_.u[e];     \
    }                                                                         \
    ak_.v = krg1; av_.v = vrg1;                                               \
    _Pragma("unroll")                                                         \
    for (int e = 0; e < 4; ++e) {                                             \
        *(uint32_t*)&kS[BUF][(y1 + 1) * 70 + 4 + xs1 + 2 * e] = ak_.u[e];     \
        *(uint32_t*)&vS[BUF][(y1 + 1) * 70 + 4 + xs1 + 2 * e] = av_.u[e];     \
    }                                                                         \
} while (0)

    LOADB(0);
    WRITEB(0);

    #pragma unroll
    for (int b = 0; b < 4; ++b) {
        const int buf = b & 1;

        // q for this batch (extract before qn regs are reloaded)
        float qf[16];
        {
            union { int4 v[2]; unsigned short s[16]; } qu;
            qu.v[0] = qn0; qu.v[1] = qn1;
            #pragma unroll
            for (int i = 0; i < 16; ++i)
                qf[i] = bf16_to_f32(qu.s[i]) * 1.4426950408889634f;
        }

        // issue next batch's loads (fly under compute)
        if (b < 3) LOADB(b + 1);

        __syncthreads();   // buf's write (prologue / prev iter) visible

        // window rows h-1..h+1 -> LDS rows h..h+2; px w -> LDS col w+4
        const unsigned short* krow = &kS[buf][h * 70 + 3 + w0];
        const unsigned short* vrow = &vS[buf][h * 70 + 3 + w0];

        float kcw[3][3], vcw[3][3];
        #pragma unroll
        for (int s = 0; s < 2; ++s)
            #pragma unroll
            for (int r = 0; r < 3; ++r) {
                kcw[s][r] = bf16_to_f32(krow[r * 70 + s]);
                vcw[s][r] = bf16_to_f32(vrow[r * 70 + s]);
            }

        float total = 0.f;
        #pragma unroll
        for (int i = 0; i < 16; ++i) {
            const int s2 = (i + 2) % 3;
            #pragma unroll
            for (int r = 0; r < 3; ++r) {
                kcw[s2][r] = bf16_to_f32(krow[r * 70 + i + 2]);
                vcw[s2][r] = bf16_to_f32(vrow[r * 70 + i + 2]);
            }
            const float q2 = qf[i];
            float num = 0.f, den = 0.f;
            #pragma unroll
            for (int r = 0; r < 3; ++r)
                #pragma unroll
                for (int dx = 0; dx < 3; ++dx) {
                    const int sl = (i + dx) % 3;
                    float e = __builtin_exp2f(q2 * (kcw[sl][r] + relv[r * 3 + dx]));
                    den += e;
                    num = fmaf(e, vcw[sl][r], num);
                }
            total += fmaxf(num * __builtin_amdgcn_rcpf(den), 0.f);
        }

        // stage next batch into the other buffer (waits on its global loads)
        if (b < 3) WRITEB(buf ^ 1);

        #pragma unroll
        for (int off = 32; off; off >>= 1) total += __shfl_down(total, off);
        if ((tid & 63) == 0) red[b][tid >> 6] = total;
        // next iter's barrier orders red-write vs final read; buf^1 write vs readers
    }
#undef LOADB
#undef WRITEB

    __syncthreads();
    if (tid < 4)
        pooled[tid * COUT + c] =
            (red[tid][0] + red[tid][1] + red[tid][2] + red[tid][3]) * (1.f / 4096.f);
}

// ---- classifier heads ----
__global__ __launch_bounds__(256) void heads_kernel(
    const float* __restrict__ pooled,    // [4][COUT]
    const float* __restrict__ w_sp, const float* __restrict__ b_sp,
    const float* __restrict__ w_fa, const float* __restrict__ b_fa,
    const float* __restrict__ w_or, const float* __restrict__ b_or,
    float* __restrict__ out)             // [4][NOUT]
{
    const int lane   = threadIdx.x & 63;
    const int wave   = blockIdx.x * (blockDim.x >> 6) + (threadIdx.x >> 6);
    const int nwaves = gridDim.x * (blockDim.x >> 6);

    float pr[4][8];
    #pragma unroll
    for (int b = 0; b < 4; ++b)
        #pragma unroll
        for (int e = 0; e < 8; ++e)
            pr[b][e] = pooled[b * COUT + lane * 8 + e];

    for (int j = wave; j < NOUT; j += nwaves) {
        const float* __restrict__ wrow;
        float bias;
        if (j < NSPE)            { wrow = w_sp + (size_t)j * COUT;          bias = b_sp[j]; }
        else if (j < NSPE + NFAM){ wrow = w_fa + (size_t)(j - NSPE) * COUT; bias = b_fa[j - NSPE]; }
        else                     { wrow = w_or + (size_t)(j - NSPE - NFAM) * COUT; bias = b_or[j - NSPE - NFAM]; }

        const float4 w0 = reinterpret_cast<const float4*>(wrow)[lane * 2 + 0];
        const float4 w1 = reinterpret_cast<const float4*>(wrow)[lane * 2 + 1];
        const float we[8] = {w0.x, w0.y, w0.z, w0.w, w1.x, w1.y, w1.z, w1.w};

        float a0 = 0.f, a1 = 0.f, a2 = 0.f, a3 = 0.f;
        #pragma unroll
        for (int e = 0; e < 8; ++e) {
            a0 += we[e] * pr[0][e];
            a1 += we[e] * pr[1][e];
            a2 += we[e] * pr[2][e];
            a3 += we[e] * pr[3][e];
        }
        #pragma unroll
        for (int off = 32; off; off >>= 1) {
            a0 += __shfl_down(a0, off);
            a1 += __shfl_down(a1, off);
            a2 += __shfl_down(a2, off);
            a3 += __shfl_down(a3, off);
        }
        if (lane == 0) {
            out[0 * NOUT + j] = a0 + bias;
            out[1 * NOUT + j] = a1 + bias;
            out[2 * NOUT + j] = a2 + bias;
            out[3 * NOUT + j] = a3 + bias;
        }
    }
}

extern "C" void kernel_launch(void* const* d_in, const int* in_sizes, int n_in,
                              void* d_out, int out_size, void* d_ws, size_t ws_size,
                              hipStream_t stream) {
    const float* x     = (const float*)d_in[0];
    const float* wq    = (const float*)d_in[1];
    const float* bq    = (const float*)d_in[2];
    const float* wk    = (const float*)d_in[3];
    const float* bk    = (const float*)d_in[4];
    const float* wv    = (const float*)d_in[5];
    const float* bv    = (const float*)d_in[6];
    const float* rel_h = (const float*)d_in[7];
    const float* rel_w = (const float*)d_in[8];
    const float* w_sp  = (const float*)d_in[9];
    const float* b_sp  = (const float*)d_in[10];
    const float* w_fa  = (const float*)d_in[11];
    const float* b_fa  = (const float*)d_in[12];
    const float* w_or  = (const float*)d_in[13];
    const float* b_or  = (const float*)d_in[14];
    float* out = (float*)d_out;

    // ws: Wt bf16 | Xt bf16 | qkv bf16 | pooled f32
    short* Wt  = (short*)d_ws;                       // 3*512*256   = 393216
    short* Xt  = Wt + 393216;                        // 4*256*4096  = 4194304
    short* qkv = Xt + 4194304;                       // 4*3*512*4096= 25165824
    float* pooled = (float*)(qkv + 25165824);        // 4*512

    convert_kernel<<<dim3(8, 32, 5), 256, 0, stream>>>(x, wq, wk, wv, Xt, Wt);
    qkv_mfma_kernel<<<dim3(32, 4, 12), 256, 0, stream>>>(Wt, Xt, bq, bk, bv, qkv);
    attn_pool_kernel<<<dim3(COUT), 256, 0, stream>>>(
        (const unsigned short*)qkv, rel_h, rel_w, pooled);
    heads_kernel<<<dim3(2048), 256, 0, stream>>>(
        pooled, w_sp, b_sp, w_fa, b_fa, w_or, b_or, out);
}